// Round 1
// baseline (505.564 us; speedup 1.0000x reference)
//
#include <hip/hip_runtime.h>

#define NEV 1000000
#define POUT 4096
#define PIN 16384

// features (4,8,16384) -> featT (16384, 32): featT[p*32 + c] = features[c*16384 + p]
__global__ __launch_bounds__(256) void feat_transpose_k(const float* __restrict__ f,
                                                        float* __restrict__ ft) {
    int tid = blockIdx.x * 256 + threadIdx.x;
    if (tid < 32 * PIN) {
        int c = tid >> 14;      // /16384
        int p = tid & (PIN - 1);
        ft[p * 32 + c] = f[tid];
    }
}

__global__ __launch_bounds__(256, 2) void quadconv_k(
    const float* __restrict__ features,
    const float* __restrict__ eval_locs,
    const float* __restrict__ quad_weights,
    const float* __restrict__ W0,
    const float* __restrict__ W1,
    const float* __restrict__ W2,
    const int* __restrict__ eio,   // eval_idx_out, sorted
    const int* __restrict__ eii,   // eval_idx_in
    const float* __restrict__ featT,
    int use_ft,
    float* __restrict__ out)       // (4, 8, 4096)
{
    __shared__ float sW0[128];     // (2,64)
    __shared__ float sW1[4096];    // (64,64) row-major by k
    __shared__ float sW2T[4096];   // transposed: sW2T[ij*64 + k] = W2[k*64 + ij]

    const int t = threadIdx.x;
    if (t < 128) sW0[t] = W0[t];
    for (int i = t; i < 4096; i += 256) sW1[i] = W1[i];
    for (int i = t; i < 4096; i += 256) {
        int k = i >> 6, ij = i & 63;
        sW2T[ij * 64 + k] = W2[i];
    }
    __syncthreads();

    const int lane = t & 63;
    const int p = blockIdx.x * 4 + (t >> 6);   // one wave per output segment

    // binary search segment boundaries in sorted eio (wave-uniform, broadcast loads)
    int lo = 0, hi = NEV;
    while (lo < hi) { int m = (lo + hi) >> 1; if (eio[m] < p) lo = m + 1; else hi = m; }
    const int start = lo;
    hi = NEV;
    while (lo < hi) { int m = (lo + hi) >> 1; if (eio[m] <= p) lo = m + 1; else hi = m; }
    const int end = lo;

    float acc[32];   // acc[b*8+j]
    #pragma unroll
    for (int i = 0; i < 32; ++i) acc[i] = 0.f;

    for (int e = start + lane; e < end; e += 64) {
        const float2 x = ((const float2*)eval_locs)[e];
        const int ii = eii[e];

        // bump * quadrature weight
        const float r2 = x.x * x.x + x.y * x.y;
        const float dd = 1.0f - 1048576.0f * r2 * r2;     // 1 - DECAY*r4, >= 0.329
        const float w = __expf(1.0f - 1.0f / dd) * quad_weights[ii];

        // layers 1+2 fused: h1[j] = sum_k sin(x . W0[:,k]) * W1[k][j]  (pre-activation)
        float h1[64];
        #pragma unroll
        for (int j = 0; j < 64; ++j) h1[j] = 0.f;
        #pragma unroll 1
        for (int k = 0; k < 64; ++k) {
            const float h0k = __sinf(fmaf(x.x, sW0[k], x.y * sW0[64 + k]));
            const float4* row = (const float4*)(sW1 + (k << 6));
            #pragma unroll
            for (int q = 0; q < 16; ++q) {
                const float4 wv = row[q];
                h1[4*q+0] = fmaf(h0k, wv.x, h1[4*q+0]);
                h1[4*q+1] = fmaf(h0k, wv.y, h1[4*q+1]);
                h1[4*q+2] = fmaf(h0k, wv.z, h1[4*q+2]);
                h1[4*q+3] = fmaf(h0k, wv.w, h1[4*q+3]);
            }
        }
        #pragma unroll
        for (int j = 0; j < 64; ++j) h1[j] = __sinf(h1[j]);

        // layer 3 + einsum, fused. filt[i][j] = sum_k h1[k] * W2[k][i*8+j]
        #pragma unroll 1
        for (int i = 0; i < 8; ++i) {
            float g0, g1, g2, g3;   // gathered[b][i] for b=0..3
            if (use_ft) {
                const float* gp = featT + ii * 32 + i;
                g0 = gp[0]; g1 = gp[8]; g2 = gp[16]; g3 = gp[24];
            } else {
                g0 = features[(0 * 8 + i) * PIN + ii];
                g1 = features[(1 * 8 + i) * PIN + ii];
                g2 = features[(2 * 8 + i) * PIN + ii];
                g3 = features[(3 * 8 + i) * PIN + ii];
            }
            g0 *= w; g1 *= w; g2 *= w; g3 *= w;
            #pragma unroll
            for (int j = 0; j < 8; ++j) {
                const float4* row = (const float4*)(sW2T + ((i * 8 + j) << 6));
                float s0 = 0.f, s1 = 0.f, s2 = 0.f, s3 = 0.f;
                #pragma unroll
                for (int q = 0; q < 16; ++q) {
                    const float4 wv = row[q];
                    s0 = fmaf(h1[4*q+0], wv.x, s0);
                    s1 = fmaf(h1[4*q+1], wv.y, s1);
                    s2 = fmaf(h1[4*q+2], wv.z, s2);
                    s3 = fmaf(h1[4*q+3], wv.w, s3);
                }
                const float f = (s0 + s1) + (s2 + s3);
                acc[0*8+j] = fmaf(g0, f, acc[0*8+j]);
                acc[1*8+j] = fmaf(g1, f, acc[1*8+j]);
                acc[2*8+j] = fmaf(g2, f, acc[2*8+j]);
                acc[3*8+j] = fmaf(g3, f, acc[3*8+j]);
            }
        }
    }

    // wave-level reduction of the 32 accumulators; no atomics (one wave owns segment p)
    float myval = 0.f;
    #pragma unroll
    for (int v = 0; v < 32; ++v) {
        float s = acc[v];
        s += __shfl_xor(s, 1, 64);
        s += __shfl_xor(s, 2, 64);
        s += __shfl_xor(s, 4, 64);
        s += __shfl_xor(s, 8, 64);
        s += __shfl_xor(s, 16, 64);
        s += __shfl_xor(s, 32, 64);
        if (lane == v) myval = s;
    }
    if (lane < 32) {
        const int b = lane >> 3, j = lane & 7;
        out[b * (8 * POUT) + j * POUT + p] = myval;
    }
}

extern "C" void kernel_launch(void* const* d_in, const int* in_sizes, int n_in,
                              void* d_out, int out_size, void* d_ws, size_t ws_size,
                              hipStream_t stream) {
    const float* features  = (const float*)d_in[0];
    const float* eval_locs = (const float*)d_in[1];
    const float* qw        = (const float*)d_in[2];
    const float* W0        = (const float*)d_in[3];
    const float* W1        = (const float*)d_in[4];
    const float* W2        = (const float*)d_in[5];
    const int*   eio       = (const int*)d_in[6];
    const int*   eii       = (const int*)d_in[7];
    float* out   = (float*)d_out;
    float* featT = (float*)d_ws;

    const int use_ft = (ws_size >= (size_t)(32 * PIN) * sizeof(float)) ? 1 : 0;
    if (use_ft) {
        feat_transpose_k<<<(32 * PIN + 255) / 256, 256, 0, stream>>>(features, featT);
    }
    quadconv_k<<<POUT / 4, 256, 0, stream>>>(features, eval_locs, qw, W0, W1, W2,
                                             eio, eii, featT, use_ft, out);
}